// Round 2
// baseline (495.446 us; speedup 1.0000x reference)
//
#include <hip/hip_runtime.h>

// Masked embedding lookup:
//   out[b,h,:] = (idx[b,h] == -1) ? 0 : table[idx[b,h], :]
// Shapes: idx [4096*200] int32, table [100000,128] f32, out [4096*200,128] f32.
//
// Strategy: 32 lanes cooperate on one 128-float (512 B) row; each lane moves
// one float4. Reads and writes are fully coalesced 16 B/lane. The 51 MB table
// lives in L3 across the ~8x average row reuse, so HBM traffic is dominated
// by the 419 MB output write.

#define EMB_DIM   128
#define NO_LABEL  (-1)
#define LANES_PER_ROW 32

__global__ __launch_bounds__(256) void lookup_kernel(
    const int* __restrict__ idx,
    const float* __restrict__ table,
    float* __restrict__ out,
    int n_rows)
{
    const int gtid = blockIdx.x * blockDim.x + threadIdx.x;
    const int row  = gtid >> 5;        // 32 threads per row
    const int lane = gtid & 31;
    if (row >= n_rows) return;

    const int id = idx[row];           // broadcast within the 32-lane group

    float4 v = make_float4(0.f, 0.f, 0.f, 0.f);
    if (id != NO_LABEL) {
        const float4* __restrict__ src =
            (const float4*)(table + (size_t)id * EMB_DIM);
        v = src[lane];
    }

    float4* __restrict__ dst = (float4*)(out + (size_t)row * EMB_DIM);
    dst[lane] = v;
}

extern "C" void kernel_launch(void* const* d_in, const int* in_sizes, int n_in,
                              void* d_out, int out_size, void* d_ws, size_t ws_size,
                              hipStream_t stream) {
    const int*   idx   = (const int*)d_in[0];    // input_batch, int32 per harness
    const float* table = (const float*)d_in[1];  // [100000,128] f32
    float*       out   = (float*)d_out;          // [B*H,128] f32

    const int n_rows = in_sizes[0];              // 4096*200 = 819200
    const int total_threads = n_rows * LANES_PER_ROW;
    const int block = 256;
    const int grid  = (total_threads + block - 1) / block;

    lookup_kernel<<<grid, block, 0, stream>>>(idx, table, out, n_rows);
}